// Round 8
// baseline (792.017 us; speedup 1.0000x reference)
//
#include <hip/hip_runtime.h>

// Reference collapses: softmax over a size-1 key axis == 1.0, so
// out[bn,t,:] = padded[bn,t,:] + (masked_mean_t(padded[bn]) @ Wv + bv).
// q/k/rope/positions/sum_token are dead code.
//
// R12: single dispatch, "last-finisher-does-the-rest".  Evidence so far:
//  - splitting dispatches costs ~13us gap each (R0/R6/R11 totals);
//  - few fat lockstep blocks serialize phases at 2.2-2.6 TB/s (R5-R10);
//  - many small independent blocks DO stream at ~5+ TB/s (R0 K1/K3).
// So: 2048 small blocks (8/CU backfill), 4 per bn.  Each block does a
// quarter-tile masked partial colsum (48 KB read) -> ws, threadfence,
// atomicAdd on a per-bn counter.  The 4th finisher (always already
// scheduled -> no spin, no deadlock, dispatch-order-independent) reduces
// the 4 partials, does the matvec (Wv once per bn, L2-hot), and streams
// out = padded + v for the whole bn (re-read L2/L3-hot: siblings just
// touched it; sibling quads mapped to the SAME XCD via %8 round-robin).
// Thin blocks retire instantly -> continuous backfill; fat finalizers are
// spread uniformly through the dispatch stream.  Counters zeroed by a
// 2 KB hipMemsetAsync node (graph-capture-safe).

#define DM 384
#define TT 128
#define C4 96          // DM / 4
#define BN_TOT 512
#define NBLK (BN_TOT * 4)

typedef float f32x4 __attribute__((ext_vector_type(4)));

__device__ __forceinline__ void nt_store4(float4* p, const float4 v) {
    __builtin_nontemporal_store(*(const f32x4*)&v, (f32x4*)p);
}

__global__ __launch_bounds__(384) void fused_lastblock(
    const float* __restrict__ padded,
    const int*   __restrict__ masks,
    const float* __restrict__ Wv,
    const float* __restrict__ bv,
    unsigned int* __restrict__ ws_cnt,   // (BN)     zeroed by memset node
    float*        __restrict__ ws_den,   // (BN, 4)
    float*        __restrict__ ws_part,  // (BN, 4, DM)
    float*        __restrict__ out)
{
    const int b = blockIdx.x;
    // sibling quads on the same XCD (blockIdx round-robins XCDs by %8):
    // xcd = b&7, quarter = (b>>3)&3, bn = (b>>5)*8 + xcd.
    const int q  = (b >> 3) & 3;
    const int bn = ((b >> 5) << 3) | (b & 7);

    const int t  = threadIdx.x;
    const int c  = t % C4;               // float4 col 0..95
    const int rr = t / C4;               // 0..3

    __shared__ float  w_sh[32];
    __shared__ float4 part[4][C4];       // 6 KB (reused by matvec)
    __shared__ float  summ[DM];
    __shared__ float  v_sh[DM];
    __shared__ int    last_sh;

    if (t < 32) w_sh[t] = (float)masks[bn * TT + q * 32 + t];
    __syncthreads();

    // ---- phase A: quarter-tile masked partial colsum (48 KB read) ----
    const float4* __restrict__ p4q =
        (const float4*)padded + (size_t)bn * TT * C4 + (size_t)q * 32 * C4;

    float4 acc = make_float4(0.f, 0.f, 0.f, 0.f);
    #pragma unroll
    for (int j = 0; j < 8; ++j) {
        const int   r = rr + 4 * j;      // 0..31 within quarter
        const float w = w_sh[r];
        const float4 xv = p4q[r * C4 + c];
        acc.x += xv.x * w; acc.y += xv.y * w;
        acc.z += xv.z * w; acc.w += xv.w * w;
    }
    part[rr][c] = acc;
    __syncthreads();

    if (t < C4) {
        const float4 a0 = part[0][t], a1 = part[1][t];
        const float4 a2 = part[2][t], a3 = part[3][t];
        float4 s;
        s.x = (a0.x + a1.x) + (a2.x + a3.x);
        s.y = (a0.y + a1.y) + (a2.y + a3.y);
        s.z = (a0.z + a1.z) + (a2.z + a3.z);
        s.w = (a0.w + a1.w) + (a2.w + a3.w);
        ((float4*)(ws_part + ((size_t)bn * 4 + q) * DM))[t] = s;
    } else if (t == C4) {
        float s0 = 0.f, s1 = 0.f, s2 = 0.f, s3 = 0.f;
        #pragma unroll
        for (int i = 0; i < 8; ++i) {
            s0 += w_sh[i];      s1 += w_sh[8 + i];
            s2 += w_sh[16 + i]; s3 += w_sh[24 + i];
        }
        ws_den[bn * 4 + q] = (s0 + s1) + (s2 + s3);
    }

    // ---- release: make partials device-visible, then count in ----
    __threadfence();
    __syncthreads();
    if (t == 0) {
        const unsigned int old = atomicAdd(&ws_cnt[bn], 1u);
        last_sh = (old == 3u);
    }
    __syncthreads();
    if (!last_sh) return;                // thin blocks retire -> backfill

    // ======== finalizer (1 of 4, order-independent, no spin) ========
    __threadfence();                     // acquire: see siblings' partials

    // ---- summary = (sum of 4 partials) / denom ----
    {
        const float* __restrict__ pp = ws_part + (size_t)bn * 4 * DM;
        const float  s = (pp[t] + pp[DM + t]) + (pp[2 * DM + t] + pp[3 * DM + t]);
        const float* __restrict__ dd = ws_den + bn * 4;
        const float  den = (dd[0] + dd[1]) + (dd[2] + dd[3]);
        summ[t] = s * (1.0f / fmaxf(den, 1e-6f));
    }
    __syncthreads();

    // ---- matvec: thread (c, rr) covers e in [rr*96, rr*96+96) ----
    {
        float4 a = make_float4(0.f, 0.f, 0.f, 0.f);
        const float4* __restrict__ wv4 = (const float4*)Wv;
        #pragma unroll 8
        for (int j = 0; j < 96; ++j) {
            const int   e = rr * 96 + j;
            const float s = summ[e];                 // LDS broadcast
            const float4 w = wv4[(size_t)e * C4 + c]; // coalesced, L2-hot
            a.x += s * w.x; a.y += s * w.y; a.z += s * w.z; a.w += s * w.w;
        }
        part[rr][c] = a;
    }
    __syncthreads();

    if (t < C4) {
        float4 v = ((const float4*)bv)[t];
        #pragma unroll
        for (int g = 0; g < 4; ++g) {
            const float4 p = part[g][t];
            v.x += p.x; v.y += p.y; v.z += p.z; v.w += p.w;
        }
        ((float4*)v_sh)[t] = v;
    }
    __syncthreads();

    // ---- stream full bn: out = padded + v (re-read L2/L3-hot) ----
    const float4* __restrict__ p4 = (const float4*)padded + (size_t)bn * TT * C4;
    float4*       __restrict__ o4 = (float4*)out + (size_t)bn * TT * C4;
    const float4 v = ((const float4*)v_sh)[c];
    #pragma unroll
    for (int j = 0; j < 32; ++j) {
        const int r = rr + 4 * j;
        float4 xv = p4[r * C4 + c];
        xv.x += v.x; xv.y += v.y; xv.z += v.z; xv.w += v.w;
        nt_store4(&o4[r * C4 + c], xv);
    }
}

extern "C" void kernel_launch(void* const* d_in, const int* in_sizes, int n_in,
                              void* d_out, int out_size, void* d_ws, size_t ws_size,
                              hipStream_t stream) {
    const float* padded = (const float*)d_in[0];
    // d_in[1] sum_token, d_in[2] positions_3d, d_in[3..6] Wq/bq/Wk/bk: dead
    const float* Wv     = (const float*)d_in[7];
    const float* bv     = (const float*)d_in[8];
    const int*   masks  = (const int*)d_in[9];
    float* out = (float*)d_out;

    // ws layout: [cnt: 512 u32][den: 2048 f32][part: 512*4*384 f32]
    unsigned int* ws_cnt = (unsigned int*)d_ws;
    float* ws_den  = (float*)d_ws + BN_TOT;              // after 512 u32
    float* ws_part = ws_den + (size_t)BN_TOT * 4;

    hipMemsetAsync(ws_cnt, 0, BN_TOT * sizeof(unsigned int), stream);
    fused_lastblock<<<NBLK, 384, 0, stream>>>(padded, masks, Wv, bv,
                                              ws_cnt, ws_den, ws_part, out);
}

// Round 9
// 211.667 us; speedup vs baseline: 3.7418x; 3.7418x over previous
//
#include <hip/hip_runtime.h>

// Reference collapses: softmax over a size-1 key axis == 1.0, so
// out[bn,t,:] = padded[bn,t,:] + (masked_mean_t(padded[bn]) @ Wv + bv).
// q/k/rope/positions/sum_token are dead code.
//
// R13 = R8 (best: 70us kernel, 205.2 total) + one change: the store
// phase's tile re-read is issued BEFORE the matvec (it doesn't depend on
// v), pinned above it with sched_barrier(0), so its latency hides under
// the matvec's L2 loop instead of sitting naked after it.  asm pins
// removed (3x proven no-op, they only constrain the scheduler).
//
// Kept from R8 (all evidence-backed):
//  - single dispatch (R0/R6/R11: each extra dispatch costs ~13us gap)
//  - 512 fat blocks -> ~2 sequential rounds/CU: only ~50 MB of tiles in
//    flight at once, so re-reads hit L3 (FETCH 54 MB vs R9/R10's 100 MB
//    when all 512 small blocks were co-resident and thrashed L3)
//  - no cross-block communication (R12: device-scope fences on gfx950
//    writeback non-coherent XCD L2s -> 10x disaster)
//  - nontemporal stores for out (write-only; keep L3 for padded)
// Prediction: VGPR ~96-128 (prefetch lives across matvec -- if 64 again
// the compiler sank the loads and delta~0), kernel ~60-64us.

#define DM 384
#define TT 128
#define C4 96          // DM / 4
#define BN_TOT 512
#define NR  8          // row-groups (768 = 8 * 96)
#define RPT 16         // rows per thread

typedef float f32x4 __attribute__((ext_vector_type(4)));

__device__ __forceinline__ void nt_store4(float4* p, const float4 v) {
    __builtin_nontemporal_store(*(const f32x4*)&v, (f32x4*)p);
}

__global__ __launch_bounds__(768, 4) void fused_prefetch(
    const float* __restrict__ padded,
    const int*   __restrict__ masks,
    const float* __restrict__ Wv,
    const float* __restrict__ bv,
    float*       __restrict__ out)
{
    const int bn = blockIdx.x;
    const int t  = threadIdx.x;
    const int c  = t % C4;               // float4 column 0..95
    const int r  = t / C4;               // row-group 0..7

    __shared__ float  w_sh[TT];
    __shared__ float4 part_sh[NR][C4];   // 12 KB
    __shared__ float  summ[DM];

    // masks first so their waitcnt clears early
    int m = 0;
    if (t < TT) m = masks[bn * TT + t];

    const float4* __restrict__ p4 =
        (const float4*)padded + (size_t)bn * TT * C4;

    // ---- phase 1: issue all 16 tile loads upfront (deep MLP) ----
    float4 x[RPT];
    #pragma unroll
    for (int i = 0; i < RPT; ++i) x[i] = p4[(r + i * NR) * C4 + c];

    if (t < TT) w_sh[t] = (float)m;
    __syncthreads();

    // ---- masked column partial sums, 4 accumulators ----
    float4 a0 = make_float4(0.f, 0.f, 0.f, 0.f);
    float4 a1 = make_float4(0.f, 0.f, 0.f, 0.f);
    float4 a2 = make_float4(0.f, 0.f, 0.f, 0.f);
    float4 a3 = make_float4(0.f, 0.f, 0.f, 0.f);
    #pragma unroll
    for (int i = 0; i < 4; ++i) {
        const float w0 = w_sh[r + (4 * i)     * NR];
        const float w1 = w_sh[r + (4 * i + 1) * NR];
        const float w2 = w_sh[r + (4 * i + 2) * NR];
        const float w3 = w_sh[r + (4 * i + 3) * NR];
        const float4 x0 = x[4 * i], x1 = x[4 * i + 1];
        const float4 x2 = x[4 * i + 2], x3 = x[4 * i + 3];
        a0.x += x0.x * w0; a0.y += x0.y * w0; a0.z += x0.z * w0; a0.w += x0.w * w0;
        a1.x += x1.x * w1; a1.y += x1.y * w1; a1.z += x1.z * w1; a1.w += x1.w * w1;
        a2.x += x2.x * w2; a2.y += x2.y * w2; a2.z += x2.z * w2; a2.w += x2.w * w2;
        a3.x += x3.x * w3; a3.y += x3.y * w3; a3.z += x3.z * w3; a3.w += x3.w * w3;
    }
    a0.x += a1.x + a2.x + a3.x; a0.y += a1.y + a2.y + a3.y;
    a0.z += a1.z + a2.z + a3.z; a0.w += a1.w + a2.w + a3.w;
    part_sh[r][c] = a0;
    __syncthreads();

    // ---- finalize summary (96 threads; denom via 4 parallel chains) ----
    if (t < C4) {
        float d0 = 0.f, d1 = 0.f, d2 = 0.f, d3 = 0.f;
        #pragma unroll
        for (int i = 0; i < 32; ++i) {
            d0 += w_sh[i];      d1 += w_sh[32 + i];
            d2 += w_sh[64 + i]; d3 += w_sh[96 + i];
        }
        const float inv = 1.0f / fmaxf((d0 + d1) + (d2 + d3), 1e-6f);

        float4 s = part_sh[0][t];
        #pragma unroll
        for (int g = 1; g < NR; ++g) {
            const float4 p = part_sh[g][t];
            s.x += p.x; s.y += p.y; s.z += p.z; s.w += p.w;
        }
        s.x *= inv; s.y *= inv; s.z *= inv; s.w *= inv;
        ((float4*)summ)[t] = s;
    }
    __syncthreads();

    // ---- prefetch the tile re-read NOW (independent of matvec); ----
    // ---- sched_barrier(0) pins the loads above the matvec loop.  ----
    float4 y[RPT];
    #pragma unroll
    for (int i = 0; i < RPT; ++i) y[i] = p4[(r + i * NR) * C4 + c];
    __builtin_amdgcn_sched_barrier(0);

    // ---- matvec: row-group r covers Wv rows [r*48, r*48+48) ----
    float4 a = make_float4(0.f, 0.f, 0.f, 0.f);
    const float4* __restrict__ wv4 = (const float4*)Wv;
    const int e0 = r * (DM / NR);
    #pragma unroll 8
    for (int i = 0; i < DM / NR; ++i) {
        const int   e = e0 + i;
        const float s = summ[e];                    // LDS broadcast
        const float4 w = wv4[(size_t)e * C4 + c];   // coalesced, L2-hot
        a.x += s * w.x; a.y += s * w.y; a.z += s * w.z; a.w += s * w.w;
    }
    part_sh[r][c] = a;
    __syncthreads();

    // ---- v-finalize per thread (LDS broadcast, no extra barrier) ----
    float4 v = ((const float4*)bv)[c];
    #pragma unroll
    for (int g = 0; g < NR; ++g) {
        const float4 q = part_sh[g][c];
        v.x += q.x; v.y += q.y; v.z += q.z; v.w += q.w;
    }

    // ---- store: out = prefetched tile + v (loads already in flight) ----
    float4* __restrict__ o4 = (float4*)out + (size_t)bn * TT * C4;
    #pragma unroll
    for (int i = 0; i < RPT; ++i) {
        float4 z = y[i];
        z.x += v.x; z.y += v.y; z.z += v.z; z.w += v.w;
        nt_store4(&o4[(r + i * NR) * C4 + c], z);
    }
}

extern "C" void kernel_launch(void* const* d_in, const int* in_sizes, int n_in,
                              void* d_out, int out_size, void* d_ws, size_t ws_size,
                              hipStream_t stream) {
    const float* padded = (const float*)d_in[0];
    // d_in[1] sum_token, d_in[2] positions_3d, d_in[3..6] Wq/bq/Wk/bk: dead
    const float* Wv     = (const float*)d_in[7];
    const float* bv     = (const float*)d_in[8];
    const int*   masks  = (const int*)d_in[9];
    float* out = (float*)d_out;

    fused_prefetch<<<BN_TOT, 768, 0, stream>>>(padded, masks, Wv, bv, out);
}